// Round 1
// baseline (2104.444 us; speedup 1.0000x reference)
//
#include <hip/hip_runtime.h>
#include <math.h>

#define BB 2
#define SS 2048
#define DD 1024
#define HH 16
#define HD 64
#define MM (BB*SS)   // 4096

// ---------------------------------------------------------------------------
// GEMM: C[M,N] = X[M,K] @ W[K,N] + bias[N]     (all row-major fp32)
// 64x64 block tile, BK=16, 256 threads, 4x4 per thread.
// ---------------------------------------------------------------------------
__global__ __launch_bounds__(256) void gemm_bias_kernel(
        const float* __restrict__ X, const float* __restrict__ W,
        const float* __restrict__ bias, float* __restrict__ C,
        int Mdim, int N, int K) {
    constexpr int BM = 64, BN = 64, BK = 16;
    __shared__ float As[BK][BM + 1];   // k-major, padded
    __shared__ float Bs[BK][BN + 1];

    const int bx = blockIdx.x;             // M tile
    const int by = blockIdx.y;             // N tile
    const int tid = threadIdx.x;
    const int tx = tid & 15;               // 0..15 (N direction)
    const int ty = tid >> 4;               // 0..15 (M direction)
    const int row0 = ty * 4;               // local row base
    const int col0 = tx * 4;               // local col base

    float acc[4][4] = {};

    for (int k0 = 0; k0 < K; k0 += BK) {
        // A tile: 64 rows x 16 k. One float4 per thread along k.
        {
            const int r  = tid >> 2;            // 0..63
            const int kc = (tid & 3) * 4;       // 0,4,8,12
            const float4 a = *reinterpret_cast<const float4*>(
                &X[(size_t)(bx * BM + r) * K + k0 + kc]);
            As[kc + 0][r] = a.x;
            As[kc + 1][r] = a.y;
            As[kc + 2][r] = a.z;
            As[kc + 3][r] = a.w;
        }
        // B tile: 16 k x 64 cols. One float4 per thread along n.
        {
            const int kr = tid >> 4;            // 0..15
            const int c  = (tid & 15) * 4;
            const float4 b = *reinterpret_cast<const float4*>(
                &W[(size_t)(k0 + kr) * N + by * BN + c]);
            Bs[kr][c + 0] = b.x;
            Bs[kr][c + 1] = b.y;
            Bs[kr][c + 2] = b.z;
            Bs[kr][c + 3] = b.w;
        }
        __syncthreads();

        #pragma unroll
        for (int k = 0; k < BK; ++k) {
            float a[4], b[4];
            #pragma unroll
            for (int i = 0; i < 4; ++i) a[i] = As[k][row0 + i];
            #pragma unroll
            for (int j = 0; j < 4; ++j) b[j] = Bs[k][col0 + j];
            #pragma unroll
            for (int i = 0; i < 4; ++i)
                #pragma unroll
                for (int j = 0; j < 4; ++j)
                    acc[i][j] += a[i] * b[j];
        }
        __syncthreads();
    }

    const int grow = bx * BM + row0;
    const int gcol = by * BN + col0;
    #pragma unroll
    for (int i = 0; i < 4; ++i) {
        float4 o;
        o.x = acc[i][0] + bias[gcol + 0];
        o.y = acc[i][1] + bias[gcol + 1];
        o.z = acc[i][2] + bias[gcol + 2];
        o.w = acc[i][3] + bias[gcol + 3];
        *reinterpret_cast<float4*>(&C[(size_t)(grow + i) * N + gcol]) = o;
    }
}

// ---------------------------------------------------------------------------
// RoPE (GPT-J/Llama duplicated-freq layout), applied in place to q and k.
// One thread per (b, s, h, j) with j in [0,32): rotates the (j, j+32) pair.
// ---------------------------------------------------------------------------
__global__ void rope_kernel(float* __restrict__ q, float* __restrict__ k) {
    const int idx = blockIdx.x * blockDim.x + threadIdx.x;  // B*S*H*32 total
    const int j = idx & 31;
    const int h = (idx >> 5) & (HH - 1);
    const int s = (idx >> 9) & (SS - 1);
    const int b = idx >> 20;

    const float inv_freq = 1.0f / powf(10000.0f, (2.0f * j) / (float)HD);
    const float f  = (float)s * inv_freq;
    const float sn = sinf(f);
    const float cs = cosf(f);

    const size_t base = ((size_t)(b * SS + s)) * DD + h * HD;
    const float q1 = q[base + j], q2 = q[base + j + 32];
    q[base + j]      = q1 * cs - q2 * sn;
    q[base + j + 32] = q2 * cs + q1 * sn;
    const float k1 = k[base + j], k2 = k[base + j + 32];
    k[base + j]      = k1 * cs - k2 * sn;
    k[base + j + 32] = k2 * cs + k1 * sn;
}

// ---------------------------------------------------------------------------
// Causal flash attention, fp32. One thread per query row.
// Block = 256 threads = 256 query rows for one (b, h).
// K/V staged in LDS in 64-key tiles. Online softmax w/ lazy rescale.
// ---------------------------------------------------------------------------
__global__ __launch_bounds__(256) void attn_kernel(
        const float* __restrict__ q, const float* __restrict__ k,
        const float* __restrict__ v, float* __restrict__ out) {
    const int bh = blockIdx.x;         // 0 .. B*H-1
    const int b  = bh / HH;
    const int h  = bh % HH;
    const int q0 = blockIdx.y * 256;
    const int tid = threadIdx.x;
    const int qi = q0 + tid;

    __shared__ float Ks[64][HD];
    __shared__ float Vs[64][HD];

    float4 qv[16];
    {
        const size_t qbase = ((size_t)(b * SS + qi)) * DD + h * HD;
        #pragma unroll
        for (int i = 0; i < 16; ++i)
            qv[i] = *reinterpret_cast<const float4*>(&q[qbase + 4 * i]);
    }

    float m = -INFINITY;
    float l = 0.0f;
    float4 acc[16];
    #pragma unroll
    for (int i = 0; i < 16; ++i) acc[i] = make_float4(0.f, 0.f, 0.f, 0.f);

    const int kmax = q0 + 255;                  // last key any thread needs
    for (int s0 = 0; s0 <= kmax; s0 += 64) {
        // cooperative K/V tile load: 64 rows x 64 floats each
        for (int c = tid; c < 64 * (HD / 4); c += 256) {
            const int r  = c >> 4;              // 0..63
            const int cc = (c & 15) * 4;
            const size_t base = ((size_t)(b * SS + s0 + r)) * DD + h * HD + cc;
            *reinterpret_cast<float4*>(&Ks[r][cc]) =
                *reinterpret_cast<const float4*>(&k[base]);
            *reinterpret_cast<float4*>(&Vs[r][cc]) =
                *reinterpret_cast<const float4*>(&v[base]);
        }
        __syncthreads();

        const int jend = min(64, qi - s0 + 1);  // causal bound for this thread
        for (int j = 0; j < jend; ++j) {
            const float4* Kr = reinterpret_cast<const float4*>(Ks[j]);
            float sc = 0.f;
            #pragma unroll
            for (int i = 0; i < 16; ++i) {
                const float4 kk = Kr[i];
                sc += qv[i].x * kk.x + qv[i].y * kk.y +
                      qv[i].z * kk.z + qv[i].w * kk.w;
            }
            sc *= 0.125f;                       // 1/sqrt(64)
            const float4* Vr = reinterpret_cast<const float4*>(Vs[j]);
            if (sc <= m) {
                const float p = __expf(sc - m);
                l += p;
                #pragma unroll
                for (int i = 0; i < 16; ++i) {
                    const float4 vv = Vr[i];
                    acc[i].x += p * vv.x; acc[i].y += p * vv.y;
                    acc[i].z += p * vv.z; acc[i].w += p * vv.w;
                }
            } else {
                const float corr = __expf(m - sc);
                m = sc;
                l = l * corr + 1.0f;
                #pragma unroll
                for (int i = 0; i < 16; ++i) {
                    const float4 vv = Vr[i];
                    acc[i].x = acc[i].x * corr + vv.x;
                    acc[i].y = acc[i].y * corr + vv.y;
                    acc[i].z = acc[i].z * corr + vv.z;
                    acc[i].w = acc[i].w * corr + vv.w;
                }
            }
        }
        __syncthreads();
    }

    const float inv_l = 1.0f / l;
    const size_t obase = ((size_t)(b * SS + qi)) * DD + h * HD;
    #pragma unroll
    for (int i = 0; i < 16; ++i) {
        float4 o;
        o.x = acc[i].x * inv_l; o.y = acc[i].y * inv_l;
        o.z = acc[i].z * inv_l; o.w = acc[i].w * inv_l;
        *reinterpret_cast<float4*>(&out[obase + 4 * i]) = o;
    }
}

// ---------------------------------------------------------------------------
extern "C" void kernel_launch(void* const* d_in, const int* in_sizes, int n_in,
                              void* d_out, int out_size, void* d_ws, size_t ws_size,
                              hipStream_t stream) {
    const float* x  = (const float*)d_in[0];
    // d_in[1] = boolean causal mask — ignored; causality is hardcoded (matches tril mask).
    const float* Wq = (const float*)d_in[2];
    const float* bq = (const float*)d_in[3];
    const float* Wk = (const float*)d_in[4];
    const float* bk = (const float*)d_in[5];
    const float* Wv = (const float*)d_in[6];
    const float* bv = (const float*)d_in[7];
    const float* Wo = (const float*)d_in[8];
    const float* bo = (const float*)d_in[9];
    float* out = (float*)d_out;

    float* q    = (float*)d_ws;              // 4096*1024 floats = 16 MB
    float* k    = q + (size_t)MM * DD;
    float* v    = k + (size_t)MM * DD;
    float* attn = v + (size_t)MM * DD;       // total 64 MB

    const dim3 gg(MM / 64, DD / 64);
    const dim3 blk(256);

    gemm_bias_kernel<<<gg, blk, 0, stream>>>(x, Wq, bq, q, MM, DD, DD);
    gemm_bias_kernel<<<gg, blk, 0, stream>>>(x, Wk, bk, k, MM, DD, DD);
    gemm_bias_kernel<<<gg, blk, 0, stream>>>(x, Wv, bv, v, MM, DD, DD);

    rope_kernel<<<(BB * SS * HH * 32) / 256, 256, 0, stream>>>(q, k);

    attn_kernel<<<dim3(BB * HH, SS / 256), blk, 0, stream>>>(q, k, v, attn);

    gemm_bias_kernel<<<gg, blk, 0, stream>>>(attn, Wo, bo, out, MM, DD, DD);
}

// Round 3
// 189.994 us; speedup vs baseline: 11.0764x; 11.0764x over previous
//
#include <hip/hip_runtime.h>
#include <math.h>

typedef unsigned short u16;
typedef unsigned int   u32;
typedef __attribute__((ext_vector_type(8))) short bf16x8;
typedef __attribute__((ext_vector_type(4))) short s16x4;
typedef __attribute__((ext_vector_type(4))) float f32x4;

#define BB 2
#define SS 2048
#define DD 1024
#define HH 16
#define HD 64
#define MM (BB*SS)   // 4096

// ---------------------------------------------------------------------------
// bf16 helpers (self-contained, no hip_bf16 header dependence)
// ---------------------------------------------------------------------------
__device__ __forceinline__ u16 f2bf(float f) {
    u32 u = __float_as_uint(f);
    u32 r = (u + 0x7fffu + ((u >> 16) & 1u)) >> 16;   // RNE
    return (u16)r;
}
__device__ __forceinline__ float bf2f(u16 h) {
    return __uint_as_float(((u32)h) << 16);
}
__device__ __forceinline__ u32 cvt_pk_bf16(float lo, float hi) {
    u32 r;
    asm("v_cvt_pk_bf16_f32 %0, %1, %2" : "=v"(r) : "v"(lo), "v"(hi));
    return r;
}

// ---------------------------------------------------------------------------
// cast fp32 -> bf16 (vectorized, memory-bound)
// ---------------------------------------------------------------------------
__global__ __launch_bounds__(256) void cast_f32_bf16(
        const float* __restrict__ src, u16* __restrict__ dst, int n4) {
    int i = blockIdx.x * 256 + threadIdx.x;
    if (i >= n4) return;
    float4 v = reinterpret_cast<const float4*>(src)[i];
    u32 lo = (u32)f2bf(v.x) | ((u32)f2bf(v.y) << 16);
    u32 hi = (u32)f2bf(v.z) | ((u32)f2bf(v.w) << 16);
    reinterpret_cast<uint2*>(dst)[i] = make_uint2(lo, hi);
}

// ---------------------------------------------------------------------------
// transpose + cast the four 1024x1024 weight matrices: Wt[n][k] = (bf16)W[k][n]
// so GEMM B-fragments become contiguous-K row loads.
// ---------------------------------------------------------------------------
__global__ __launch_bounds__(256) void transpose_cast_w(
        const float* __restrict__ W0, const float* __restrict__ W1,
        const float* __restrict__ W2, const float* __restrict__ W3,
        u16* __restrict__ T0, u16* __restrict__ T1,
        u16* __restrict__ T2, u16* __restrict__ T3) {
    const float* W; u16* T;
    switch (blockIdx.z) {
        case 0:  W = W0; T = T0; break;
        case 1:  W = W1; T = T1; break;
        case 2:  W = W2; T = T2; break;
        default: W = W3; T = T3; break;
    }
    __shared__ float L[64][65];
    const int t  = threadIdx.x;
    const int k0 = blockIdx.x * 64, n0 = blockIdx.y * 64;
    #pragma unroll
    for (int rep = 0; rep < 4; ++rep) {
        int row = rep * 16 + (t >> 4);
        int col = (t & 15) * 4;
        float4 v = *reinterpret_cast<const float4*>(&W[(size_t)(k0 + row) * DD + n0 + col]);
        L[row][col] = v.x; L[row][col+1] = v.y; L[row][col+2] = v.z; L[row][col+3] = v.w;
    }
    __syncthreads();
    #pragma unroll
    for (int rep = 0; rep < 2; ++rep) {
        int q  = t + rep * 256;
        int n  = q >> 3, sl = q & 7;
        u32 w[4];
        #pragma unroll
        for (int e = 0; e < 4; ++e) {
            float a = L[sl*8 + 2*e][n];
            float b = L[sl*8 + 2*e + 1][n];
            w[e] = (u32)f2bf(a) | ((u32)f2bf(b) << 16);
        }
        *reinterpret_cast<uint4*>(&T[(size_t)(n0 + n) * DD + k0 + sl*8]) =
            make_uint4(w[0], w[1], w[2], w[3]);
    }
}

// ---------------------------------------------------------------------------
// bf16 MFMA GEMM: C[M,N] = A[M,K] @ W + bias, with W given transposed (Bt[N][K]).
// BM=128, BN=64, BK=32, 256 threads (4 waves 2x2), 8 MFMA per K-step.
// ---------------------------------------------------------------------------
template <typename OT>
__global__ __launch_bounds__(256) void gemm_bf16(
        const u16* __restrict__ A, const u16* __restrict__ Bt,
        const float* __restrict__ bias, OT* __restrict__ C, int N) {
    constexpr int K = DD;
    __shared__ u16 As[128 * 32];
    __shared__ u16 Bs[64 * 32];
    const int tid  = threadIdx.x;
    const int lane = tid & 63, wid = tid >> 6;
    const int g = lane >> 4, c = lane & 15;
    const int wr = wid >> 1, wc = wid & 1;
    const int rowbase = blockIdx.x * 128;
    const int colbase = blockIdx.y * 64;

    f32x4 zz = {0.f, 0.f, 0.f, 0.f};
    f32x4 acc[4][2];
    #pragma unroll
    for (int i = 0; i < 4; ++i)
        #pragma unroll
        for (int j = 0; j < 2; ++j) acc[i][j] = zz;

    for (int k0 = 0; k0 < K; k0 += 32) {
        if (k0) __syncthreads();
        // reg-staged A tile [128][32]
        #pragma unroll
        for (int rep = 0; rep < 2; ++rep) {
            int q = tid + rep * 256;
            int row = q >> 2, sl = q & 3;
            *reinterpret_cast<uint4*>(&As[row*32 + sl*8]) =
                *reinterpret_cast<const uint4*>(&A[(size_t)(rowbase + row) * K + k0 + sl*8]);
        }
        // B tile [64][32] (rows of W^T)
        {
            int row = tid >> 2, sl = tid & 3;
            *reinterpret_cast<uint4*>(&Bs[row*32 + sl*8]) =
                *reinterpret_cast<const uint4*>(&Bt[(size_t)(colbase + row) * K + k0 + sl*8]);
        }
        __syncthreads();

        bf16x8 af[4], bfr[2];
        #pragma unroll
        for (int mi = 0; mi < 4; ++mi)
            af[mi] = *reinterpret_cast<const bf16x8*>(&As[(wr*64 + mi*16 + c)*32 + g*8]);
        #pragma unroll
        for (int nj = 0; nj < 2; ++nj)
            bfr[nj] = *reinterpret_cast<const bf16x8*>(&Bs[(wc*32 + nj*16 + c)*32 + g*8]);
        #pragma unroll
        for (int mi = 0; mi < 4; ++mi)
            #pragma unroll
            for (int nj = 0; nj < 2; ++nj)
                acc[mi][nj] = __builtin_amdgcn_mfma_f32_16x16x32_bf16(
                    af[mi], bfr[nj], acc[mi][nj], 0, 0, 0);
    }

    #pragma unroll
    for (int mi = 0; mi < 4; ++mi)
        #pragma unroll
        for (int nj = 0; nj < 2; ++nj) {
            int colg = colbase + wc*32 + nj*16 + c;
            float bv = bias[colg];
            #pragma unroll
            for (int r = 0; r < 4; ++r) {
                int rowg = rowbase + wr*64 + mi*16 + g*4 + r;
                float v = acc[mi][nj][r] + bv;
                if constexpr (sizeof(OT) == 2) C[(size_t)rowg * N + colg] = (OT)f2bf(v);
                else                           C[(size_t)rowg * N + colg] = v;
            }
        }
}

// ---------------------------------------------------------------------------
// RoPE on bf16 q,k in place; folds the 1/sqrt(64)=0.125 score scale into q.
// ---------------------------------------------------------------------------
__global__ __launch_bounds__(256) void rope_bf16(u16* __restrict__ q, u16* __restrict__ k) {
    const int idx = blockIdx.x * 256 + threadIdx.x;
    const int j = idx & 31;
    const int h = (idx >> 5) & (HH - 1);
    const int s = (idx >> 9) & (SS - 1);
    const int b = idx >> 20;

    const float inv_freq = exp2f(-0.41524101186f * (float)j);  // 1/10000^(2j/64)
    const float f  = (float)s * inv_freq;
    const float sn = sinf(f);
    const float cs = cosf(f);

    const size_t base = ((size_t)(b * SS + s)) * DD + h * HD;
    float q1 = bf2f(q[base + j]), q2 = bf2f(q[base + j + 32]);
    q[base + j]      = f2bf((q1 * cs - q2 * sn) * 0.125f);
    q[base + j + 32] = f2bf((q2 * cs + q1 * sn) * 0.125f);
    float k1 = bf2f(k[base + j]), k2 = bf2f(k[base + j + 32]);
    k[base + j]      = f2bf(k1 * cs - k2 * sn);
    k[base + j + 32] = f2bf(k2 * cs + k1 * sn);
}

// ---------------------------------------------------------------------------
// Causal flash attention, bf16 MFMA, f32 softmax/accum.
// Block: 4 waves x 32 q-rows = 128 q-rows for one (b,h). K-tiles of 64.
// Swapped QK^T (mfma(K, Q^T)) so each lane holds P for its own q-column;
// P feeds PV directly via a consistent k-permutation kappa (no cross-lane moves).
// ---------------------------------------------------------------------------
__global__ __launch_bounds__(256) void attn_mfma(
        const u16* __restrict__ qb, const u16* __restrict__ kb,
        const u16* __restrict__ vb, u16* __restrict__ ob) {
    const int bid = blockIdx.x;
    const int bh  = bid & 31;
    const int qt  = 15 - (bid >> 5);         // heavy tiles first
    const int b   = bh >> 4, h = bh & 15;
    const int q0  = qt * 128;
    const int tid = threadIdx.x;
    const int lane = tid & 63, wq = tid >> 6;
    const int g = lane >> 4, c = lane & 15;
    const int qw0 = q0 + wq * 32;

    __shared__ u16 Ks[64 * 64];   // [key][hd], 16B slots XOR-swizzled by (row&7)
    __shared__ u16 Vt[64 * 68];   // transposed [d][key], +4 pad

    // Q fragments (persistent): B-operand of swapped QK^T. Q pre-scaled by 0.125.
    bf16x8 qf[2][2];
    #pragma unroll
    for (int nj = 0; nj < 2; ++nj)
        #pragma unroll
        for (int ks = 0; ks < 2; ++ks)
            qf[nj][ks] = *reinterpret_cast<const bf16x8*>(
                &qb[(size_t)(b * SS + qw0 + nj*16 + c) * DD + h*64 + ks*32 + g*8]);

    f32x4 zz = {0.f, 0.f, 0.f, 0.f};
    f32x4 of[4][2];                       // O^T fragments [d-block][q-block]
    #pragma unroll
    for (int i = 0; i < 4; ++i)
        #pragma unroll
        for (int j = 0; j < 2; ++j) of[i][j] = zz;
    float mv[2] = {-1e30f, -1e30f};
    float lv[2] = {0.f, 0.f};

    const int nkt = qt * 2 + 2;
    for (int kt = 0; kt < nkt; ++kt) {
        const int k0 = kt * 64;
        if (kt) __syncthreads();
        // stage K tile, swizzled: slot^(row&7)
        #pragma unroll
        for (int rep = 0; rep < 2; ++rep) {
            int qq = tid + rep * 256;
            int row = qq >> 3, sl = qq & 7;
            uint4 u = *reinterpret_cast<const uint4*>(
                &kb[(size_t)(b * SS + k0 + row) * DD + h*64 + sl*8]);
            *reinterpret_cast<uint4*>(&Ks[row*64 + ((sl ^ (row & 7)) * 8)]) = u;
        }
        // stage V transposed: Vt[d][key]
        #pragma unroll
        for (int rep = 0; rep < 2; ++rep) {
            int qq = tid + rep * 256;
            int vrow = qq >> 3, dsl = qq & 7;
            uint4 u = *reinterpret_cast<const uint4*>(
                &vb[(size_t)(b * SS + k0 + vrow) * DD + h*64 + dsl*8]);
            u32 ww[4] = {u.x, u.y, u.z, u.w};
            #pragma unroll
            for (int e = 0; e < 4; ++e) {
                Vt[(dsl*8 + 2*e    ) * 68 + vrow] = (u16)(ww[e] & 0xffffu);
                Vt[(dsl*8 + 2*e + 1) * 68 + vrow] = (u16)(ww[e] >> 16);
            }
        }
        __syncthreads();

        if (k0 > qw0 + 31) continue;      // wave fully masked (uniform per wave)

        // S^T[64k][32q] = K-tile @ Q^T
        f32x4 sf[4][2];
        #pragma unroll
        for (int i = 0; i < 4; ++i)
            #pragma unroll
            for (int j = 0; j < 2; ++j) sf[i][j] = zz;
        #pragma unroll
        for (int ks = 0; ks < 2; ++ks)
            #pragma unroll
            for (int mi = 0; mi < 4; ++mi) {
                int row = mi*16 + c;
                bf16x8 kf = *reinterpret_cast<const bf16x8*>(
                    &Ks[row*64 + (((ks*4 + g) ^ (row & 7)) * 8)]);
                #pragma unroll
                for (int nj = 0; nj < 2; ++nj)
                    sf[mi][nj] = __builtin_amdgcn_mfma_f32_16x16x32_bf16(
                        kf, qf[nj][ks], sf[mi][nj], 0, 0, 0);
            }

        // causal mask (only diagonal-ish tiles)
        if (k0 + 64 > qw0) {
            #pragma unroll
            for (int mi = 0; mi < 4; ++mi) {
                int key = k0 + mi*16 + g*4;
                #pragma unroll
                for (int nj = 0; nj < 2; ++nj) {
                    int qv = qw0 + nj*16 + c;
                    #pragma unroll
                    for (int r = 0; r < 4; ++r)
                        if (key + r > qv) sf[mi][nj][r] = -1e30f;
                }
            }
        }

        // online softmax per q-column group; pack P to bf16 fragments
        union PB { u32 u[4]; bf16x8 v; } pb[2][2];
        #pragma unroll
        for (int nj = 0; nj < 2; ++nj) {
            float pmax = -1e30f;
            #pragma unroll
            for (int mi = 0; mi < 4; ++mi)
                #pragma unroll
                for (int r = 0; r < 4; ++r) pmax = fmaxf(pmax, sf[mi][nj][r]);
            pmax = fmaxf(pmax, __shfl_xor(pmax, 16));
            pmax = fmaxf(pmax, __shfl_xor(pmax, 32));
            float mnew = fmaxf(mv[nj], pmax);
            float corr = __expf(mv[nj] - mnew);
            mv[nj] = mnew;
            float p[4][4]; float ls = 0.f;
            #pragma unroll
            for (int mi = 0; mi < 4; ++mi)
                #pragma unroll
                for (int r = 0; r < 4; ++r) {
                    float e = __expf(sf[mi][nj][r] - mnew);
                    p[mi][r] = e; ls += e;
                }
            ls += __shfl_xor(ls, 16);
            ls += __shfl_xor(ls, 32);
            lv[nj] = lv[nj] * corr + ls;
            #pragma unroll
            for (int mid = 0; mid < 4; ++mid) of[mid][nj] *= corr;
            #pragma unroll
            for (int ks = 0; ks < 2; ++ks) {
                pb[nj][ks].u[0] = cvt_pk_bf16(p[2*ks][0],     p[2*ks][1]);
                pb[nj][ks].u[1] = cvt_pk_bf16(p[2*ks][2],     p[2*ks][3]);
                pb[nj][ks].u[2] = cvt_pk_bf16(p[2*ks + 1][0], p[2*ks + 1][1]);
                pb[nj][ks].u[3] = cvt_pk_bf16(p[2*ks + 1][2], p[2*ks + 1][3]);
            }
        }

        // O^T += V^T @ P^T   (A-frag from Vt with the same kappa as P)
        #pragma unroll
        for (int mid = 0; mid < 4; ++mid) {
            int d = mid*16 + c;
            #pragma unroll
            for (int ks = 0; ks < 2; ++ks) {
                union { s16x4 hh[2]; bf16x8 v; } vv;
                vv.hh[0] = *reinterpret_cast<const s16x4*>(&Vt[d*68 + ks*32 + 4*g]);
                vv.hh[1] = *reinterpret_cast<const s16x4*>(&Vt[d*68 + ks*32 + 16 + 4*g]);
                #pragma unroll
                for (int nj = 0; nj < 2; ++nj)
                    of[mid][nj] = __builtin_amdgcn_mfma_f32_16x16x32_bf16(
                        vv.v, pb[nj][ks].v, of[mid][nj], 0, 0, 0);
            }
        }
    }

    // normalize and write attention output (bf16)
    #pragma unroll
    for (int nj = 0; nj < 2; ++nj) {
        float inv = 1.0f / lv[nj];
        int qv = qw0 + nj*16 + c;
        #pragma unroll
        for (int mid = 0; mid < 4; ++mid)
            #pragma unroll
            for (int r = 0; r < 4; ++r) {
                int d = mid*16 + g*4 + r;
                ob[(size_t)(b * SS + qv) * DD + h*64 + d] = f2bf(of[mid][nj][r] * inv);
            }
    }
}

// ---------------------------------------------------------------------------
extern "C" void kernel_launch(void* const* d_in, const int* in_sizes, int n_in,
                              void* d_out, int out_size, void* d_ws, size_t ws_size,
                              hipStream_t stream) {
    const float* x  = (const float*)d_in[0];
    // d_in[1] = boolean causal mask — ignored; causality hardcoded (matches tril).
    const float* Wq = (const float*)d_in[2];
    const float* bq = (const float*)d_in[3];
    const float* Wk = (const float*)d_in[4];
    const float* bk = (const float*)d_in[5];
    const float* Wv = (const float*)d_in[6];
    const float* bv = (const float*)d_in[7];
    const float* Wo = (const float*)d_in[8];
    const float* bo = (const float*)d_in[9];
    float* out = (float*)d_out;

    u16* Xb   = (u16*)d_ws;                      // 8 MB
    u16* Wqt  = Xb  + (size_t)MM * DD;           // 2 MB each
    u16* Wkt  = Wqt + (size_t)DD * DD;
    u16* Wvt  = Wkt + (size_t)DD * DD;
    u16* Wot  = Wvt + (size_t)DD * DD;
    u16* qbuf = Wot + (size_t)DD * DD;           // 8 MB each
    u16* kbuf = qbuf + (size_t)MM * DD;
    u16* vbuf = kbuf + (size_t)MM * DD;
    u16* abuf = vbuf + (size_t)MM * DD;          // total 48 MB

    cast_f32_bf16<<<(MM * DD / 4) / 256, 256, 0, stream>>>(x, Xb, MM * DD / 4);
    transpose_cast_w<<<dim3(16, 16, 4), 256, 0, stream>>>(Wq, Wk, Wv, Wo, Wqt, Wkt, Wvt, Wot);

    gemm_bf16<u16><<<dim3(32, 16), 256, 0, stream>>>(Xb, Wqt, bq, qbuf, DD);
    gemm_bf16<u16><<<dim3(32, 16), 256, 0, stream>>>(Xb, Wkt, bk, kbuf, DD);
    gemm_bf16<u16><<<dim3(32, 16), 256, 0, stream>>>(Xb, Wvt, bv, vbuf, DD);

    rope_bf16<<<(BB * SS * HH * 32) / 256, 256, 0, stream>>>(qbuf, kbuf);

    attn_mfma<<<512, 256, 0, stream>>>(qbuf, kbuf, vbuf, abuf);

    gemm_bf16<float><<<dim3(32, 16), 256, 0, stream>>>(abuf, Wot, bo, out, DD);
}

// Round 6
// 147.893 us; speedup vs baseline: 14.2295x; 1.2847x over previous
//
#include <hip/hip_runtime.h>
#include <math.h>

typedef unsigned short u16;
typedef unsigned int   u32;
typedef __attribute__((ext_vector_type(8))) short bf16x8;
typedef __attribute__((ext_vector_type(4))) short s16x4;
typedef __attribute__((ext_vector_type(4))) float f32x4;

#define BB 2
#define SS 2048
#define DD 1024
#define HH 16
#define HD 64
#define MM (BB*SS)   // 4096
#define QKVN 3072

// ---------------------------------------------------------------------------
// helpers
// ---------------------------------------------------------------------------
__device__ __forceinline__ u16 f2bf(float f) {
    u32 u = __float_as_uint(f);
    return (u16)((u + 0x7fffu + ((u >> 16) & 1u)) >> 16);   // RNE
}
__device__ __forceinline__ float bf2f(u16 h) {
    return __uint_as_float(((u32)h) << 16);
}
__device__ __forceinline__ u32 cvt_pk_bf16(float lo, float hi) {
    u32 r;
    asm("v_cvt_pk_bf16_f32 %0, %1, %2" : "=v"(r) : "v"(lo), "v"(hi));
    return r;
}
// async global->LDS, 16B per lane; LDS dest = wave-uniform base + lane*16.
__device__ __forceinline__ void gload16(const void* g, void* l) {
    __builtin_amdgcn_global_load_lds(
        (const __attribute__((address_space(1))) u32*)g,
        (__attribute__((address_space(3))) u32*)l, 16, 0, 0);
}

// ---------------------------------------------------------------------------
// cast fp32 -> bf16
// ---------------------------------------------------------------------------
__global__ __launch_bounds__(256) void cast_f32_bf16(
        const float* __restrict__ src, u16* __restrict__ dst, int n4) {
    int i = blockIdx.x * 256 + threadIdx.x;
    if (i >= n4) return;
    float4 v = reinterpret_cast<const float4*>(src)[i];
    u32 lo = (u32)f2bf(v.x) | ((u32)f2bf(v.y) << 16);
    u32 hi = (u32)f2bf(v.z) | ((u32)f2bf(v.w) << 16);
    reinterpret_cast<uint2*>(dst)[i] = make_uint2(lo, hi);
}

__global__ __launch_bounds__(256) void concat_bias(
        const float* __restrict__ a, const float* __restrict__ b,
        const float* __restrict__ c, float* __restrict__ o) {
    int i = blockIdx.x * 256 + threadIdx.x;   // 3072 total
    float v = (i < 1024) ? a[i] : (i < 2048) ? b[i - 1024] : c[i - 2048];
    o[i] = v;
}

// ---------------------------------------------------------------------------
// transpose + cast weights: T[n][k] = (bf16)W[k][n]
// ---------------------------------------------------------------------------
__global__ __launch_bounds__(256) void transpose_cast_w(
        const float* __restrict__ W0, const float* __restrict__ W1,
        const float* __restrict__ W2, const float* __restrict__ W3,
        u16* __restrict__ T0, u16* __restrict__ T1,
        u16* __restrict__ T2, u16* __restrict__ T3) {
    const float* W; u16* T;
    switch (blockIdx.z) {
        case 0:  W = W0; T = T0; break;
        case 1:  W = W1; T = T1; break;
        case 2:  W = W2; T = T2; break;
        default: W = W3; T = T3; break;
    }
    __shared__ float L[64][65];
    const int t  = threadIdx.x;
    const int k0 = blockIdx.x * 64, n0 = blockIdx.y * 64;
    #pragma unroll
    for (int rep = 0; rep < 4; ++rep) {
        int row = rep * 16 + (t >> 4);
        int col = (t & 15) * 4;
        float4 v = *reinterpret_cast<const float4*>(&W[(size_t)(k0 + row) * DD + n0 + col]);
        L[row][col] = v.x; L[row][col+1] = v.y; L[row][col+2] = v.z; L[row][col+3] = v.w;
    }
    __syncthreads();
    #pragma unroll
    for (int rep = 0; rep < 2; ++rep) {
        int q  = t + rep * 256;
        int n  = q >> 3, sl = q & 7;
        u32 w[4];
        #pragma unroll
        for (int e = 0; e < 4; ++e) {
            float a = L[sl*8 + 2*e][n];
            float b = L[sl*8 + 2*e + 1][n];
            w[e] = (u32)f2bf(a) | ((u32)f2bf(b) << 16);
        }
        *reinterpret_cast<uint4*>(&T[(size_t)(n0 + n) * DD + k0 + sl*8]) =
            make_uint4(w[0], w[1], w[2], w[3]);
    }
}

// ---------------------------------------------------------------------------
// bf16 MFMA GEMM, m97 structure: BM=BN=128, BK=32, 4 waves (2x2), each wave
// 64x64 (4x4 frags). global_load_lds w16 staging, double LDS, one barrier/iter.
// C[M,N] = A[M,1024] @ Bt^T + bias   (Bt is [N][1024] row-major)
// ---------------------------------------------------------------------------
template <typename OT>
__global__ __launch_bounds__(256) void gemm_bf16(
        const u16* __restrict__ A, const u16* __restrict__ Bt,
        const float* __restrict__ bias, OT* __restrict__ C, int N) {
    constexpr int K = DD;
    __shared__ __align__(16) u16 As[2][128 * 32];
    __shared__ __align__(16) u16 Bs[2][128 * 32];
    const int tid  = threadIdx.x;
    const int lane = tid & 63, w = tid >> 6;
    const int g = lane >> 4, c = lane & 15;
    const int wr = w >> 1, wc = w & 1;
    const int rowbase = blockIdx.x * 128;
    const int colbase = blockIdx.y * 128;

    auto stage = [&](int t, int bf) {
        const int k0 = t * 32;
        #pragma unroll
        for (int i = 0; i < 2; ++i) {
            int row = w * 32 + i * 16 + (lane >> 2);
            int sl  = lane & 3;
            gload16(&A [(size_t)(rowbase + row) * K + k0 + sl * 8],
                    &As[bf][(w * 32 + i * 16) * 32]);
            gload16(&Bt[(size_t)(colbase + row) * K + k0 + sl * 8],
                    &Bs[bf][(w * 32 + i * 16) * 32]);
        }
    };

    f32x4 acc[4][4];
    #pragma unroll
    for (int i = 0; i < 4; ++i)
        #pragma unroll
        for (int j = 0; j < 4; ++j) acc[i][j] = (f32x4){0.f, 0.f, 0.f, 0.f};

    stage(0, 0);
    __syncthreads();

    for (int t = 0; t < K / 32; ++t) {
        const int cur = t & 1;
        if (t + 1 < K / 32) stage(t + 1, cur ^ 1);
        bf16x8 af[4], bfr[4];
        #pragma unroll
        for (int mi = 0; mi < 4; ++mi)
            af[mi] = *reinterpret_cast<const bf16x8*>(
                &As[cur][(wr * 64 + mi * 16 + c) * 32 + g * 8]);
        #pragma unroll
        for (int nj = 0; nj < 4; ++nj)
            bfr[nj] = *reinterpret_cast<const bf16x8*>(
                &Bs[cur][(wc * 64 + nj * 16 + c) * 32 + g * 8]);
        #pragma unroll
        for (int mi = 0; mi < 4; ++mi)
            #pragma unroll
            for (int nj = 0; nj < 4; ++nj)
                acc[mi][nj] = __builtin_amdgcn_mfma_f32_16x16x32_bf16(
                    af[mi], bfr[nj], acc[mi][nj], 0, 0, 0);
        __syncthreads();
    }

    #pragma unroll
    for (int mi = 0; mi < 4; ++mi)
        #pragma unroll
        for (int nj = 0; nj < 4; ++nj) {
            int colg = colbase + wc * 64 + nj * 16 + c;
            float bv = bias[colg];
            #pragma unroll
            for (int r = 0; r < 4; ++r) {
                int rowg = rowbase + wr * 64 + mi * 16 + g * 4 + r;
                float v = acc[mi][nj][r] + bv;
                if constexpr (sizeof(OT) == 2) C[(size_t)rowg * N + colg] = (OT)f2bf(v);
                else                           C[(size_t)rowg * N + colg] = v;
            }
        }
}

// ---------------------------------------------------------------------------
// RoPE in place on fused qkv buffer (stride 3072); folds 0.125 into q.
// ---------------------------------------------------------------------------
__global__ __launch_bounds__(256) void rope_bf16(u16* __restrict__ qkv) {
    const int idx = blockIdx.x * 256 + threadIdx.x;
    const int j = idx & 31;
    const int h = (idx >> 5) & (HH - 1);
    const int s = (idx >> 9) & (SS - 1);
    const int b = idx >> 20;

    const float inv_freq = exp2f(-0.41524101186f * (float)j);  // 1/10000^(2j/64)
    const float f  = (float)s * inv_freq;
    const float sn = sinf(f);
    const float cs = cosf(f);

    u16* q = qkv;
    u16* k = qkv + 1024;
    const size_t base = ((size_t)(b * SS + s)) * QKVN + h * HD;
    float q1 = bf2f(q[base + j]), q2 = bf2f(q[base + j + 32]);
    q[base + j]      = f2bf((q1 * cs - q2 * sn) * 0.125f);
    q[base + j + 32] = f2bf((q2 * cs + q1 * sn) * 0.125f);
    float k1 = bf2f(k[base + j]), k2 = bf2f(k[base + j + 32]);
    k[base + j]      = f2bf(k1 * cs - k2 * sn);
    k[base + j + 32] = f2bf(k2 * cs + k1 * sn);
}

// ---------------------------------------------------------------------------
// Causal flash attention — round-3-proven data path (reg-staged swizzled K,
// explicit Vt transpose, __expf online softmax), with equal-work tile pairing:
// block handles tiles (15-p, p), so every block runs exactly 34 k-iters.
// 4 waves x 32 q-rows = 128-row q-tiles. Inputs strided QKVN (fused buffer).
// ---------------------------------------------------------------------------
__global__ __launch_bounds__(256) void attn_mfma(
        const u16* __restrict__ qb, const u16* __restrict__ kb,
        const u16* __restrict__ vb, u16* __restrict__ ob) {
    const int bid = blockIdx.x;          // 256 = 32 bh x 8 pairs
    const int bh  = bid & 31;
    const int p   = bid >> 5;            // 0..7
    const int b   = bh >> 4, h = bh & 15;
    const int tid = threadIdx.x;
    const int lane = tid & 63, wq = tid >> 6;
    const int g = lane >> 4, c = lane & 15;

    __shared__ u16 Ks[64 * 64];   // [key][hd], 16B slots XOR-swizzled by (row&7)
    __shared__ u16 Vt[64 * 68];   // transposed [d][key], +4 pad

    for (int half = 0; half < 2; ++half) {
        const int qt  = half ? p : (15 - p);     // heavy tile first
        const int qw0 = qt * 128 + wq * 32;
        const int nkt = qt * 2 + 2;

        // persistent Q fragments (B-operand of swapped QK^T), pre-scaled 0.125
        bf16x8 qf[2][2];
        #pragma unroll
        for (int nj = 0; nj < 2; ++nj)
            #pragma unroll
            for (int ks = 0; ks < 2; ++ks)
                qf[nj][ks] = *reinterpret_cast<const bf16x8*>(
                    &qb[(size_t)(b * SS + qw0 + nj*16 + c) * QKVN + h*64 + ks*32 + g*8]);

        f32x4 of[4][2];                       // O^T fragments [d-block][q-block]
        #pragma unroll
        for (int i = 0; i < 4; ++i)
            #pragma unroll
            for (int j = 0; j < 2; ++j) of[i][j] = (f32x4){0.f, 0.f, 0.f, 0.f};
        float mv[2] = {-1e30f, -1e30f};
        float lv[2] = {0.f, 0.f};

        for (int kt = 0; kt < nkt; ++kt) {
            const int k0 = kt * 64;
            __syncthreads();                     // protect LDS from prev compute
            // stage K tile, swizzled: slot^(row&7)
            #pragma unroll
            for (int rep = 0; rep < 2; ++rep) {
                int qq = tid + rep * 256;
                int row = qq >> 3, sl = qq & 7;
                uint4 u = *reinterpret_cast<const uint4*>(
                    &kb[(size_t)(b * SS + k0 + row) * QKVN + h*64 + sl*8]);
                *reinterpret_cast<uint4*>(&Ks[row*64 + ((sl ^ (row & 7)) * 8)]) = u;
            }
            // stage V transposed: Vt[d][key]
            #pragma unroll
            for (int rep = 0; rep < 2; ++rep) {
                int qq = tid + rep * 256;
                int vrow = qq >> 3, dsl = qq & 7;
                uint4 u = *reinterpret_cast<const uint4*>(
                    &vb[(size_t)(b * SS + k0 + vrow) * QKVN + h*64 + dsl*8]);
                u32 ww[4] = {u.x, u.y, u.z, u.w};
                #pragma unroll
                for (int e = 0; e < 4; ++e) {
                    Vt[(dsl*8 + 2*e    ) * 68 + vrow] = (u16)(ww[e] & 0xffffu);
                    Vt[(dsl*8 + 2*e + 1) * 68 + vrow] = (u16)(ww[e] >> 16);
                }
            }
            __syncthreads();

            if (k0 > qw0 + 31) continue;      // wave fully masked (uniform per wave)

            // S^T[64k][32q] = K-tile @ Q^T
            f32x4 sf[4][2];
            #pragma unroll
            for (int i = 0; i < 4; ++i)
                #pragma unroll
                for (int j = 0; j < 2; ++j) sf[i][j] = (f32x4){0.f, 0.f, 0.f, 0.f};
            #pragma unroll
            for (int ks = 0; ks < 2; ++ks)
                #pragma unroll
                for (int mi = 0; mi < 4; ++mi) {
                    int row = mi*16 + c;
                    bf16x8 kf = *reinterpret_cast<const bf16x8*>(
                        &Ks[row*64 + (((ks*4 + g) ^ (row & 7)) * 8)]);
                    #pragma unroll
                    for (int nj = 0; nj < 2; ++nj)
                        sf[mi][nj] = __builtin_amdgcn_mfma_f32_16x16x32_bf16(
                            kf, qf[nj][ks], sf[mi][nj], 0, 0, 0);
                }

            // causal mask (only diagonal-ish tiles)
            if (k0 + 64 > qw0) {
                #pragma unroll
                for (int mi = 0; mi < 4; ++mi) {
                    int key = k0 + mi*16 + g*4;
                    #pragma unroll
                    for (int nj = 0; nj < 2; ++nj) {
                        int qv = qw0 + nj*16 + c;
                        #pragma unroll
                        for (int r = 0; r < 4; ++r)
                            if (key + r > qv) sf[mi][nj][r] = -1e30f;
                    }
                }
            }

            // online softmax per q-column group; pack P to bf16 fragments
            union PB { u32 u[4]; bf16x8 v; } pb[2][2];
            #pragma unroll
            for (int nj = 0; nj < 2; ++nj) {
                float pmax = -1e30f;
                #pragma unroll
                for (int mi = 0; mi < 4; ++mi)
                    #pragma unroll
                    for (int r = 0; r < 4; ++r) pmax = fmaxf(pmax, sf[mi][nj][r]);
                pmax = fmaxf(pmax, __shfl_xor(pmax, 16));
                pmax = fmaxf(pmax, __shfl_xor(pmax, 32));
                float mnew = fmaxf(mv[nj], pmax);
                float corr = __expf(mv[nj] - mnew);
                mv[nj] = mnew;
                float pp[4][4]; float ls = 0.f;
                #pragma unroll
                for (int mi = 0; mi < 4; ++mi)
                    #pragma unroll
                    for (int r = 0; r < 4; ++r) {
                        float e = __expf(sf[mi][nj][r] - mnew);
                        pp[mi][r] = e; ls += e;
                    }
                ls += __shfl_xor(ls, 16);
                ls += __shfl_xor(ls, 32);
                lv[nj] = lv[nj] * corr + ls;
                #pragma unroll
                for (int mid = 0; mid < 4; ++mid) of[mid][nj] *= corr;
                #pragma unroll
                for (int ks = 0; ks < 2; ++ks) {
                    pb[nj][ks].u[0] = cvt_pk_bf16(pp[2*ks][0],     pp[2*ks][1]);
                    pb[nj][ks].u[1] = cvt_pk_bf16(pp[2*ks][2],     pp[2*ks][3]);
                    pb[nj][ks].u[2] = cvt_pk_bf16(pp[2*ks + 1][0], pp[2*ks + 1][1]);
                    pb[nj][ks].u[3] = cvt_pk_bf16(pp[2*ks + 1][2], pp[2*ks + 1][3]);
                }
            }

            // O^T += V^T @ P^T   (A-frag from Vt with the same kappa as P)
            #pragma unroll
            for (int mid = 0; mid < 4; ++mid) {
                int d = mid*16 + c;
                #pragma unroll
                for (int ks = 0; ks < 2; ++ks) {
                    union { s16x4 hh[2]; bf16x8 v; } vv;
                    vv.hh[0] = *reinterpret_cast<const s16x4*>(&Vt[d*68 + ks*32 + 4*g]);
                    vv.hh[1] = *reinterpret_cast<const s16x4*>(&Vt[d*68 + ks*32 + 16 + 4*g]);
                    #pragma unroll
                    for (int nj = 0; nj < 2; ++nj)
                        of[mid][nj] = __builtin_amdgcn_mfma_f32_16x16x32_bf16(
                            vv.v, pb[nj][ks].v, of[mid][nj], 0, 0, 0);
                }
            }
        }

        // normalize and write attention output (bf16, stride DD)
        #pragma unroll
        for (int nj = 0; nj < 2; ++nj) {
            float inv = 1.0f / lv[nj];
            int qv = qw0 + nj*16 + c;
            #pragma unroll
            for (int mid = 0; mid < 4; ++mid) {
                u32 lo = cvt_pk_bf16(of[mid][nj][0] * inv, of[mid][nj][1] * inv);
                u32 hi = cvt_pk_bf16(of[mid][nj][2] * inv, of[mid][nj][3] * inv);
                *reinterpret_cast<uint2*>(
                    &ob[(size_t)(b * SS + qv) * DD + h*64 + mid*16 + g*4]) =
                    make_uint2(lo, hi);
            }
        }
    }
}

// ---------------------------------------------------------------------------
extern "C" void kernel_launch(void* const* d_in, const int* in_sizes, int n_in,
                              void* d_out, int out_size, void* d_ws, size_t ws_size,
                              hipStream_t stream) {
    const float* x  = (const float*)d_in[0];
    // d_in[1] = boolean causal mask — ignored; causality hardcoded (matches tril).
    const float* Wq = (const float*)d_in[2];
    const float* bq = (const float*)d_in[3];
    const float* Wk = (const float*)d_in[4];
    const float* bk = (const float*)d_in[5];
    const float* Wv = (const float*)d_in[6];
    const float* bv = (const float*)d_in[7];
    const float* Wo = (const float*)d_in[8];
    const float* bo = (const float*)d_in[9];
    float* out = (float*)d_out;

    u16* Xb   = (u16*)d_ws;                        //  8 MB  [4096][1024]
    u16* Wcat = Xb   + (size_t)MM * DD;            //  6 MB  [3072][1024] (q,k,v ^T)
    u16* Wot  = Wcat + (size_t)3 * DD * DD;        //  2 MB  [1024][1024]
    u16* qkv  = Wot  + (size_t)DD * DD;            // 24 MB  [4096][3072]
    u16* abuf = qkv  + (size_t)MM * QKVN;          //  8 MB  [4096][1024]
    float* bcat = (float*)(abuf + (size_t)MM * DD);// 12 KB

    cast_f32_bf16<<<(MM * DD / 4) / 256, 256, 0, stream>>>(x, Xb, MM * DD / 4);
    concat_bias<<<12, 256, 0, stream>>>(bq, bk, bv, bcat);
    transpose_cast_w<<<dim3(16, 16, 4), 256, 0, stream>>>(
        Wq, Wk, Wv, Wo,
        Wcat, Wcat + (size_t)DD * DD, Wcat + (size_t)2 * DD * DD, Wot);

    // fused QKV projection: [4096,1024] @ [1024,3072]
    gemm_bf16<u16><<<dim3(32, 24), 256, 0, stream>>>(Xb, Wcat, bcat, qkv, QKVN);

    rope_bf16<<<(BB * SS * HH * 32) / 256, 256, 0, stream>>>(qkv);

    attn_mfma<<<256, 256, 0, stream>>>(qkv, qkv + 1024, qkv + 2048, abuf);

    // output projection
    gemm_bf16<float><<<dim3(32, 8), 256, 0, stream>>>(abuf, Wot, bo, out, DD);
}